// Round 15
// baseline (325.304 us; speedup 1.0000x reference)
//
#include <hip/hip_runtime.h>
#include <math.h>

#define D_MODEL 1024
#define NUM_HEADS 16
#define DK 64
#define BATCH 2
#define NSEQ 2048
#define MROWS (BATCH * NSEQ)   // 4096

typedef __attribute__((ext_vector_type(8))) short bf16x8;
typedef __attribute__((ext_vector_type(4))) short s16x4;
typedef __attribute__((ext_vector_type(4))) float f32x4;
typedef unsigned short u16;

static __device__ __forceinline__ u16 f2bf_rne(float x) {
    union { float f; unsigned u; } v; v.f = x;
    unsigned r = v.u + 0x7fffu + ((v.u >> 16) & 1u);
    return (u16)(r >> 16);
}
static __device__ __forceinline__ void split_bf16(float x, u16& hi, u16& lo) {
    union { float f; unsigned u; } v; v.f = x;
    unsigned hb = v.u & 0xffff0000u;
    hi = (u16)(hb >> 16);
    union { unsigned u; float f; } hv; hv.u = hb;
    lo = f2bf_rne(x - hv.f);
}
// HW packed f32->bf16 RNE: dst.lo = bf16(a), dst.hi = bf16(b). Bit-identical
// to f2bf_rne for finite values (both round-to-nearest-even).
static __device__ __forceinline__ unsigned cvt_pk_bf16(float a, float b) {
    unsigned w;
    asm("v_cvt_pk_bf16_f32 %0, %1, %2" : "=v"(w) : "v"(a), "v"(b));
    return w;
}
static __device__ __forceinline__ float max3f(float a, float b, float c) {
    return fmaxf(fmaxf(a, b), c);   // clang fuses to v_max3_f32
}

#define AS1 __attribute__((address_space(1)))
#define AS3 __attribute__((address_space(3)))
static __device__ __forceinline__ void gl_lds16(const void* g, void* l) {
    __builtin_amdgcn_global_load_lds((AS1 void*)(uintptr_t)g, (AS3 void*)l, 16, 0, 0);
}

// ---------------------------------------------------------------------------
// fp32 -> split bf16 planes, up to 4 tensors per launch (blockIdx.y).
// ---------------------------------------------------------------------------
struct SplitN { const float* src[4]; u16* h[4]; u16* l[4]; };
__global__ __launch_bounds__(256)
void split_multi(SplitN args, int n8)
{
    const int w = blockIdx.y;
    const int i = blockIdx.x * 256 + threadIdx.x;
    if (i >= n8) return;
    const float* src = args.src[w];
    float4 a = ((const float4*)src)[2 * i];
    float4 b = ((const float4*)src)[2 * i + 1];
    float x[8] = {a.x, a.y, a.z, a.w, b.x, b.y, b.z, b.w};
    u16 hh[8], ll[8];
#pragma unroll
    for (int j = 0; j < 8; ++j) split_bf16(x[j], hh[j], ll[j]);
    *(uint4*)(args.h[w] + 8 * (size_t)i) = *(uint4*)hh;
    *(uint4*)(args.l[w] + 8 * (size_t)i) = *(uint4*)ll;
}

// ---------------------------------------------------------------------------
// Batched MFMA GEMM (R5 structure, UNCHANGED): BM=128 BN=64 BK=64.
// Used for mode 2 (V -> Vt transpose, epilogue hard-wired to BN=64=DK) and
// (R15) again for the O-projection: the wide O-proj had only 256 blocks =
// 1 block/CU = 1 wave/SIMD -> no latency hiding; this kernel runs 512
// blocks at 2-3 blocks/CU.
// ---------------------------------------------------------------------------
#define GBM 128
#define GBN 64
#define GBK 64

struct GemmDesc {
    const u16 *Ah, *Al, *Wh, *Wl;
    const float* bias;
    float* outF;
    u16 *outH, *outL;
    float scale;
    int mode;
};
struct GemmBatch { GemmDesc d[3]; };

__global__ __launch_bounds__(256)
void gemm_mfma_batch(GemmBatch batch, int M, int N, int K)
{
    __shared__ u16 SM[2 * GBM * GBK + 2 * GBN * GBK];   // 48 KB pool
    u16* As_h = SM;                       // [128][64]
    u16* As_l = SM + GBM * GBK;
    u16* Ws_h = SM + 2 * GBM * GBK;       // [64][64]
    u16* Ws_l = SM + 2 * GBM * GBK + GBN * GBK;

    const GemmDesc d = batch.d[blockIdx.z];
    const int tid  = threadIdx.x;
    const int wv   = tid >> 6, lane = tid & 63;
    const int quad = lane >> 4, lcol = lane & 15;
    const int bm = blockIdx.x * GBM, bn = blockIdx.y * GBN;   // x = M (XCD fix)
    const int wm = (wv >> 1) * 64, wn = (wv & 1) * 32;
    const int sj = lane >> 3, sg = lane & 7;
    const int sgx8 = ((sg ^ sj) << 3);

    f32x4 acc[4][2];
#pragma unroll
    for (int i = 0; i < 4; ++i)
#pragma unroll
        for (int j = 0; j < 2; ++j) acc[i][j] = (f32x4){0.f, 0.f, 0.f, 0.f};

    for (int k0 = 0; k0 < K; k0 += GBK) {
        __syncthreads();
#pragma unroll
        for (int c = 0; c < 4; ++c) {
            const int r0 = wv * 32 + c * 8;
            gl_lds16(d.Ah + (size_t)(bm + r0 + sj) * K + k0 + sgx8, As_h + r0 * GBK);
            gl_lds16(d.Al + (size_t)(bm + r0 + sj) * K + k0 + sgx8, As_l + r0 * GBK);
        }
#pragma unroll
        for (int c = 0; c < 2; ++c) {
            const int r0 = wv * 16 + c * 8;
            gl_lds16(d.Wh + (size_t)(bn + r0 + sj) * K + k0 + sgx8, Ws_h + r0 * GBK);
            gl_lds16(d.Wl + (size_t)(bn + r0 + sj) * K + k0 + sgx8, Ws_l + r0 * GBK);
        }
        __syncthreads();

#pragma unroll
        for (int hf = 0; hf < 2; ++hf) {
            const int sl = ((((hf << 2) + quad) ^ (lcol & 7)) << 3);
            bf16x8 bh[2], bl[2];
#pragma unroll
            for (int j = 0; j < 2; ++j) {
                const int rn = wn + (j << 4) + lcol;
                bh[j] = *(const bf16x8*)(Ws_h + rn * GBK + sl);
                bl[j] = *(const bf16x8*)(Ws_l + rn * GBK + sl);
            }
#pragma unroll
            for (int i = 0; i < 4; ++i) {
                const int rm = wm + (i << 4) + lcol;
                bf16x8 ah = *(const bf16x8*)(As_h + rm * GBK + sl);
                bf16x8 al = *(const bf16x8*)(As_l + rm * GBK + sl);
#pragma unroll
                for (int j = 0; j < 2; ++j) {
                    acc[i][j] = __builtin_amdgcn_mfma_f32_16x16x32_bf16(ah, bh[j], acc[i][j], 0, 0, 0);
                    acc[i][j] = __builtin_amdgcn_mfma_f32_16x16x32_bf16(al, bh[j], acc[i][j], 0, 0, 0);
                    acc[i][j] = __builtin_amdgcn_mfma_f32_16x16x32_bf16(ah, bl[j], acc[i][j], 0, 0, 0);
                }
            }
        }
    }

    if (d.mode == 2) {
        // V path: re-transpose via LDS, write Vt[b][h][d][n] single RNE plane.
        const int TS = 136;
        u16* T = SM;
        __syncthreads();
#pragma unroll
        for (int j = 0; j < 2; ++j) {
            const int cl = wn + (j << 4) + lcol;       // d-local 0..63
            const float bj = d.bias[bn + cl];
#pragma unroll
            for (int i = 0; i < 4; ++i) {
                const int r0 = wm + (i << 4) + quad * 4;
                u16 pk[4];
#pragma unroll
                for (int r = 0; r < 4; ++r) pk[r] = f2bf_rne(acc[i][j][r] + bj);
                *(ushort4*)(T + cl * TS + r0) = *(ushort4*)pk;
            }
        }
        __syncthreads();
        const int dd = tid >> 2, pt = tid & 3;
        const int bidx = bm >> 11, hh = bn >> 6;
        u16* dst = d.outH + ((size_t)(bidx * NUM_HEADS + hh) * DK + dd) * NSEQ
                 + (bm & (NSEQ - 1)) + pt * 32;
        const u16* src = T + dd * TS + pt * 32;
#pragma unroll
        for (int k = 0; k < 4; ++k)
            ((uint4*)dst)[k] = *(const uint4*)(src + 8 * k);
        return;
    }

#pragma unroll
    for (int j = 0; j < 2; ++j) {
        const int col = bn + wn + (j << 4) + lcol;
        const float bj = d.bias[col];
#pragma unroll
        for (int i = 0; i < 4; ++i) {
#pragma unroll
            for (int r = 0; r < 4; ++r) {
                const int row = bm + wm + (i << 4) + quad * 4 + r;
                const float v = (acc[i][j][r] + bj) * d.scale;
                const size_t o = (size_t)row * N + col;
                if (d.mode == 0) {
                    d.outF[o] = v;
                } else {
                    u16 hi, lo;
                    split_bf16(v, hi, lo);
                    d.outH[o] = hi;
                    d.outL[o] = lo;
                }
            }
        }
    }
}

// ---------------------------------------------------------------------------
// WIDE GEMM — BM=128 BN=128 BK=64, 256 thr (4 waves 2x2, 64x64/wave).
// R15: used ONLY for Q/K (z=2 -> 512 blocks = 2 blocks/CU, machine full).
// O-proj reverted to the old kernel: wide-O had 256 blocks = 1 block/CU =
// 1 wave/SIMD -> no latency hiding (suspected offset of QK-wide's gain).
// ---------------------------------------------------------------------------
__global__ __launch_bounds__(256)
void gemm_mfma_wide(GemmBatch batch, int M, int N, int K)
{
    __shared__ u16 SM[4 * GBM * GBK];     // 64 KB: Ah, Al, Wh, Wl [128][64]
    u16* As_h = SM;
    u16* As_l = SM + GBM * GBK;
    u16* Ws_h = SM + 2 * GBM * GBK;
    u16* Ws_l = SM + 3 * GBM * GBK;

    const GemmDesc d = batch.d[blockIdx.z];
    const int tid  = threadIdx.x;
    const int wv   = tid >> 6, lane = tid & 63;
    const int quad = lane >> 4, lcol = lane & 15;
    const int bm = blockIdx.x * GBM, bn = blockIdx.y * 128;   // x = M (XCD)
    const int wm = (wv >> 1) * 64, wn = (wv & 1) * 64;
    const int sj = lane >> 3, sg = lane & 7;
    const int sgx8 = ((sg ^ sj) << 3);

    f32x4 acc[4][4];
#pragma unroll
    for (int i = 0; i < 4; ++i)
#pragma unroll
        for (int j = 0; j < 4; ++j) acc[i][j] = (f32x4){0.f, 0.f, 0.f, 0.f};

    for (int k0 = 0; k0 < K; k0 += GBK) {
        __syncthreads();
#pragma unroll
        for (int c = 0; c < 4; ++c) {
            const int r0 = wv * 32 + c * 8;
            gl_lds16(d.Ah + (size_t)(bm + r0 + sj) * K + k0 + sgx8, As_h + r0 * GBK);
            gl_lds16(d.Al + (size_t)(bm + r0 + sj) * K + k0 + sgx8, As_l + r0 * GBK);
            gl_lds16(d.Wh + (size_t)(bn + r0 + sj) * K + k0 + sgx8, Ws_h + r0 * GBK);
            gl_lds16(d.Wl + (size_t)(bn + r0 + sj) * K + k0 + sgx8, Ws_l + r0 * GBK);
        }
        __syncthreads();

#pragma unroll
        for (int hf = 0; hf < 2; ++hf) {
            const int sl = ((((hf << 2) + quad) ^ (lcol & 7)) << 3);
            bf16x8 bh[4], bl[4];
#pragma unroll
            for (int j = 0; j < 4; ++j) {
                const int rn = wn + (j << 4) + lcol;
                bh[j] = *(const bf16x8*)(Ws_h + rn * GBK + sl);
                bl[j] = *(const bf16x8*)(Ws_l + rn * GBK + sl);
            }
#pragma unroll
            for (int i = 0; i < 4; ++i) {
                const int rm = wm + (i << 4) + lcol;
                bf16x8 ah = *(const bf16x8*)(As_h + rm * GBK + sl);
                bf16x8 al = *(const bf16x8*)(As_l + rm * GBK + sl);
#pragma unroll
                for (int j = 0; j < 4; ++j) {
                    acc[i][j] = __builtin_amdgcn_mfma_f32_16x16x32_bf16(ah, bh[j], acc[i][j], 0, 0, 0);
                    acc[i][j] = __builtin_amdgcn_mfma_f32_16x16x32_bf16(al, bh[j], acc[i][j], 0, 0, 0);
                    acc[i][j] = __builtin_amdgcn_mfma_f32_16x16x32_bf16(ah, bl[j], acc[i][j], 0, 0, 0);
                }
            }
        }
    }

#pragma unroll
    for (int j = 0; j < 4; ++j) {
        const int col = bn + wn + (j << 4) + lcol;
        const float bj = d.bias[col];
#pragma unroll
        for (int i = 0; i < 4; ++i) {
#pragma unroll
            for (int r = 0; r < 4; ++r) {
                const int row = bm + wm + (i << 4) + quad * 4 + r;
                const float v = (acc[i][j][r] + bj) * d.scale;
                const size_t o = (size_t)row * N + col;
                if (d.mode == 0) {
                    d.outF[o] = v;
                } else {
                    u16 hi, lo;
                    split_bf16(v, hi, lo);
                    d.outH[o] = hi;
                    d.outL[o] = lo;
                }
            }
        }
    }
}

// ---------------------------------------------------------------------------
// Flash attention: EXACT R12 (measured 98.6-101.3 us; MfmaUtil 30 / VALU 40
// / Occ 38 / conflicts 16.8M). Known quantity — unchanged.
// ---------------------------------------------------------------------------
__global__ __launch_bounds__(512)
void flash_attn(const u16* __restrict__ Qh_g, const u16* __restrict__ Ql_g,
                const u16* __restrict__ Kh_g, const u16* __restrict__ Kl_g,
                const u16* __restrict__ Vt_g,
                u16* __restrict__ Ch_g, u16* __restrict__ Cl_g)
{
    __shared__ __align__(16) u16 Ks_h[2][64][72], Ks_l[2][64][72];
    __shared__ __align__(16) u16 Vs[2][64][72];    // [buf][d][key]

    const int tid  = threadIdx.x;
    const int wv   = tid >> 6;          // 0..7
    const int lane = tid & 63;
    const int quad = lane >> 4;
    const int lcol = lane & 15;
    const int h    = blockIdx.x;        // XCD: head fast index (h%8 -> XCD)
    const int q0   = blockIdx.y << 7;   // 128 q per block
    const int b    = blockIdx.z;
    const size_t hbase  = (size_t)b * NSEQ * D_MODEL + (size_t)h * DK;
    const size_t vtbase = (size_t)(b * NUM_HEADS + h) * DK * NSEQ;

    // wave wv owns q rows q0 + wv*16 + lcol
    bf16x8 bQh[2], bQl[2];
    {
        const u16* qh = Qh_g + hbase + (size_t)(q0 + wv * 16 + lcol) * D_MODEL;
        const u16* ql = Ql_g + hbase + (size_t)(q0 + wv * 16 + lcol) * D_MODEL;
#pragma unroll
        for (int c = 0; c < 2; ++c) {
            bQh[c] = *(const bf16x8*)(qh + c * 32 + quad * 8);
            bQl[c] = *(const bf16x8*)(ql + c * 32 + quad * 8);
        }
    }

    f32x4 Oacc[4];
#pragma unroll
    for (int t = 0; t < 4; ++t) Oacc[t] = (f32x4){0.f, 0.f, 0.f, 0.f};
    float mrow = -INFINITY;
    float lrow = 0.f;

    // staging: 512 threads cover one 64x64 u16 plane with one uint4 each
    const int lr  = tid >> 3;           // 0..63
    const int lc8 = (tid & 7) << 3;     // u16 col 0,8,..,56

    const int NT = NSEQ / 64;           // 32 (>= 2)
    const u16* gKh = Kh_g + hbase + (size_t)lr * D_MODEL + lc8;   // row=key
    const u16* gKl = Kl_g + hbase + (size_t)lr * D_MODEL + lc8;
    const u16* gV  = Vt_g + vtbase + (size_t)lr * NSEQ + lc8;     // row=d

    // prologue: tile 0 -> buf0 (one exposed vmcnt drain, once); issue tile 1
    uint4 s0 = *(const uint4*)(gKh);
    uint4 s1 = *(const uint4*)(gKl);
    uint4 s2 = *(const uint4*)(gV);
    *(uint4*)&Ks_h[0][lr][lc8] = s0;
    *(uint4*)&Ks_l[0][lr][lc8] = s1;
    *(uint4*)&Vs[0][lr][lc8]   = s2;
    s0 = *(const uint4*)(gKh + (size_t)64 * D_MODEL);
    s1 = *(const uint4*)(gKl + (size_t)64 * D_MODEL);
    s2 = *(const uint4*)(gV + 64);
    __syncthreads();

    for (int kt = 0; kt < NT; ++kt) {
        const int cur = kt & 1;
        const u16 (*Kh)[72] = Ks_h[cur];
        const u16 (*Kl)[72] = Ks_l[cur];
        const u16 (*Vv)[72] = Vs[cur];

        f32x4 S[4];
        __builtin_amdgcn_s_setprio(1);
#pragma unroll
        for (int t = 0; t < 4; ++t) {
            bf16x8 aKh0 = *(const bf16x8*)&Kh[(t << 4) + lcol][quad * 8];
            bf16x8 aKh1 = *(const bf16x8*)&Kh[(t << 4) + lcol][32 + quad * 8];
            bf16x8 aKl0 = *(const bf16x8*)&Kl[(t << 4) + lcol][quad * 8];
            bf16x8 aKl1 = *(const bf16x8*)&Kl[(t << 4) + lcol][32 + quad * 8];
            f32x4 a = (f32x4){0.f, 0.f, 0.f, 0.f};
            a = __builtin_amdgcn_mfma_f32_16x16x32_bf16(aKh0, bQh[0], a, 0, 0, 0);
            a = __builtin_amdgcn_mfma_f32_16x16x32_bf16(aKh1, bQh[1], a, 0, 0, 0);
            a = __builtin_amdgcn_mfma_f32_16x16x32_bf16(aKl0, bQh[0], a, 0, 0, 0);
            a = __builtin_amdgcn_mfma_f32_16x16x32_bf16(aKl1, bQh[1], a, 0, 0, 0);
            a = __builtin_amdgcn_mfma_f32_16x16x32_bf16(aKh0, bQl[0], a, 0, 0, 0);
            a = __builtin_amdgcn_mfma_f32_16x16x32_bf16(aKh1, bQl[1], a, 0, 0, 0);
            S[t] = a;
        }
        __builtin_amdgcn_s_setprio(0);

        bf16x8 pb[2];
        {
            // ---- max over 16 per-lane scores, v_max3 tree ----
            float m0 = max3f(S[0][0], S[0][1], S[0][2]);
            float m1 = max3f(S[0][3], S[1][0], S[1][1]);
            float m2 = max3f(S[1][2], S[1][3], S[2][0]);
            float m3 = max3f(S[2][1], S[2][2], S[2][3]);
            float m4 = max3f(S[3][0], S[3][1], S[3][2]);
            float m16 = fmaxf(max3f(m0, m1, S[3][3]), fmaxf(m2, fmaxf(m3, m4)));
            m16 = fmaxf(m16, __shfl_xor(m16, 16, 64));
            m16 = fmaxf(m16, __shfl_xor(m16, 32, 64));
            const float mn = fmaxf(mrow, m16);
            const float alpha = __expf(mrow - mn);
            mrow = mn;

            float p[4][4];
            float psum = 0.f;
#pragma unroll
            for (int t = 0; t < 4; ++t)
#pragma unroll
                for (int r = 0; r < 4; ++r) {
                    const float pv = __expf(S[t][r] - mn);
                    p[t][r] = pv;
                    psum += pv;
                }
            psum += __shfl_xor(psum, 16, 64);
            psum += __shfl_xor(psum, 32, 64);
            lrow = alpha * lrow + psum;

            // ---- pack P^T: pb[c] = {p[2c][0..3], p[2c+1][0..3]} ----
            union { unsigned w[4]; bf16x8 v; } P0, P1;
            P0.w[0] = cvt_pk_bf16(p[0][0], p[0][1]);
            P0.w[1] = cvt_pk_bf16(p[0][2], p[0][3]);
            P0.w[2] = cvt_pk_bf16(p[1][0], p[1][1]);
            P0.w[3] = cvt_pk_bf16(p[1][2], p[1][3]);
            P1.w[0] = cvt_pk_bf16(p[2][0], p[2][1]);
            P1.w[1] = cvt_pk_bf16(p[2][2], p[2][3]);
            P1.w[2] = cvt_pk_bf16(p[3][0], p[3][1]);
            P1.w[3] = cvt_pk_bf16(p[3][2], p[3][3]);
            pb[0] = P0.v;
            pb[1] = P1.v;

#pragma unroll
            for (int t = 0; t < 4; ++t)
#pragma unroll
                for (int r = 0; r < 4; ++r) Oacc[t][r] *= alpha;
        }

        __builtin_amdgcn_s_setprio(1);
#pragma unroll
        for (int dt = 0; dt < 4; ++dt) {
            const u16* vr = &Vv[(dt << 4) + lcol][0];
#pragma unroll
            for (int c = 0; c < 2; ++c) {
                s16x4 alo = *(const s16x4*)(vr + c * 32 + quad * 4);
                s16x4 ahi = *(const s16x4*)(vr + c * 32 + 16 + quad * 4);
                bf16x8 aV;
#pragma unroll
                for (int r = 0; r < 4; ++r) { aV[r] = alo[r]; aV[4 + r] = ahi[r]; }
                Oacc[dt] = __builtin_amdgcn_mfma_f32_16x16x32_bf16(aV, pb[c], Oacc[dt], 0, 0, 0);
            }
        }
        __builtin_amdgcn_s_setprio(0);

        // write NEXT tile (staged in regs last iteration) into the other
        // buffer; its readers (iter kt+1) are behind the barrier below, its
        // previous readers (iter kt-1) finished before the last barrier.
        if (kt + 1 < NT) {
            *(uint4*)&Ks_h[cur ^ 1][lr][lc8] = s0;
            *(uint4*)&Ks_l[cur ^ 1][lr][lc8] = s1;
            *(uint4*)&Vs[cur ^ 1][lr][lc8]   = s2;
            if (kt + 2 < NT) {
                const size_t ko = (size_t)(kt + 2) << 6;
                s0 = *(const uint4*)(gKh + ko * D_MODEL);
                s1 = *(const uint4*)(gKl + ko * D_MODEL);
                s2 = *(const uint4*)(gV + ko);
            }
        }
        __syncthreads();
    }

    {
        const float inv = 1.f / lrow;
        const size_t base = hbase + (size_t)(q0 + wv * 16 + lcol) * D_MODEL;
#pragma unroll
        for (int dt = 0; dt < 4; ++dt) {
            u16 hv[4], lv[4];
#pragma unroll
            for (int r = 0; r < 4; ++r)
                split_bf16(Oacc[dt][r] * inv, hv[r], lv[r]);
            const size_t o = base + (dt << 4) + quad * 4;
            *(ushort4*)(Ch_g + o) = *(ushort4*)hv;
            *(ushort4*)(Cl_g + o) = *(ushort4*)lv;
        }
    }
}

// ---------------------------------------------------------------------------
extern "C" void kernel_launch(void* const* d_in, const int* in_sizes, int n_in,
                              void* d_out, int out_size, void* d_ws, size_t ws_size,
                              hipStream_t stream)
{
    const float* query = (const float*)d_in[0];
    const float* key_i = (const float*)d_in[1];
    const float* value = (const float*)d_in[2];
    const float* w_q   = (const float*)d_in[3];
    const float* b_q   = (const float*)d_in[4];
    const float* w_k   = (const float*)d_in[5];
    const float* b_k   = (const float*)d_in[6];
    const float* w_v   = (const float*)d_in[7];
    const float* b_v   = (const float*)d_in[8];
    const float* w_o   = (const float*)d_in[9];
    const float* b_o   = (const float*)d_in[10];
    float* out = (float*)d_out;

    const size_t WE = (size_t)D_MODEL * D_MODEL;   // 1M
    const size_t AE = (size_t)MROWS * D_MODEL;     // 4M

    u16* p = (u16*)d_ws;
    u16* Wqh = p;            u16* Wql = Wqh + WE;
    u16* Wkh = Wql + WE;     u16* Wkl = Wkh + WE;
    u16* Wvh = Wkl + WE;     u16* Wvl = Wvh + WE;
    u16* Woh = Wvl + WE;     u16* Wol = Woh + WE;
    u16* base = Wol + WE;

    SplitN ws4;
    ws4.src[0] = w_q; ws4.h[0] = Wqh; ws4.l[0] = Wql;
    ws4.src[1] = w_k; ws4.h[1] = Wkh; ws4.l[1] = Wkl;
    ws4.src[2] = w_v; ws4.h[2] = Wvh; ws4.l[2] = Wvl;
    ws4.src[3] = w_o; ws4.h[3] = Woh; ws4.l[3] = Wol;
    split_multi<<<dim3((unsigned)(WE / 8 / 256), 4), 256, 0, stream>>>(ws4, (int)(WE / 8));

    const float qscale = 0.125f;
    // XCD-aware grids: x = dimension whose blocks SHARE data.
    dim3 fgrid(NUM_HEADS, NSEQ / 128, BATCH);        // (16,16,2), x = head
    dim3 ggridQK(MROWS / GBM, D_MODEL / 128, 2);     // (32, 8, 2) wide, 2/CU
    dim3 ggrid1(MROWS / GBM, D_MODEL / GBN, 1);      // (32,16, 1) old BN=64
    const int an8 = (int)(AE / 8);

    const size_t fused_bytes = 2 * (8 * WE + 11 * AE);   // 104 MB
    if (ws_size >= fused_bytes) {
        u16* INqh = base;          u16* INql = INqh + AE;
        u16* INkh = INql + AE;     u16* INkl = INkh + AE;
        u16* INvh = INkl + AE;     u16* INvl = INvh + AE;
        u16* Qph  = INvl + AE;     u16* Qpl  = Qph + AE;
        u16* Kph  = Qpl + AE;      u16* Kpl  = Kph + AE;
        u16* VT   = Kpl + AE;
        u16* Ch   = INqh;          u16* Cl   = INql;    // alias, dead after QKV

        SplitN as3;
        as3.src[0] = query; as3.h[0] = INqh; as3.l[0] = INql;
        as3.src[1] = key_i; as3.h[1] = INkh; as3.l[1] = INkl;
        as3.src[2] = value; as3.h[2] = INvh; as3.l[2] = INvl;
        as3.src[3] = query; as3.h[3] = INqh; as3.l[3] = INql;  // unused
        split_multi<<<dim3((unsigned)(AE / 8 / 256), 3), 256, 0, stream>>>(as3, an8);

        GemmBatch gqk;
        gqk.d[0] = {INqh, INql, Wqh, Wql, b_q, nullptr, Qph, Qpl, qscale, 1};
        gqk.d[1] = {INkh, INkl, Wkh, Wkl, b_k, nullptr, Kph, Kpl, 1.0f,   1};
        gemm_mfma_wide<<<ggridQK, 256, 0, stream>>>(gqk, MROWS, D_MODEL, D_MODEL);

        GemmBatch gv;
        gv.d[0] = {INvh, INvl, Wvh, Wvl, b_v, nullptr, VT, nullptr, 1.0f, 2};
        gemm_mfma_batch<<<ggrid1, 256, 0, stream>>>(gv, MROWS, D_MODEL, D_MODEL);

        flash_attn<<<fgrid, 512, 0, stream>>>(Qph, Qpl, Kph, Kpl, VT, Ch, Cl);

        GemmBatch go;
        go.d[0] = {Ch, Cl, Woh, Wol, b_o, out, nullptr, nullptr, 1.0f, 0};
        gemm_mfma_batch<<<ggrid1, 256, 0, stream>>>(go, MROWS, D_MODEL, D_MODEL);
    } else {
        u16* INh = base;           u16* INl = INh + AE;
        u16* Qph = INl + AE;       u16* Qpl = Qph + AE;
        u16* Kph = Qpl + AE;       u16* Kpl = Kph + AE;
        u16* VT  = Kpl + AE;
        u16* Ch  = INh;            u16* Cl  = INl;

        SplitN s1;
        s1.src[0] = query; s1.h[0] = INh; s1.l[0] = INl;
        s1.src[1] = s1.src[2] = s1.src[3] = query;
        s1.h[1] = s1.h[2] = s1.h[3] = INh; s1.l[1] = s1.l[2] = s1.l[3] = INl;

        GemmBatch g;
        s1.src[0] = query;
        split_multi<<<dim3((unsigned)(AE / 8 / 256), 1), 256, 0, stream>>>(s1, an8);
        g.d[0] = {INh, INl, Wqh, Wql, b_q, nullptr, Qph, Qpl, qscale, 1};
        gemm_mfma_batch<<<ggrid1, 256, 0, stream>>>(g, MROWS, D_MODEL, D_MODEL);

        s1.src[0] = key_i;
        split_multi<<<dim3((unsigned)(AE / 8 / 256), 1), 256, 0, stream>>>(s1, an8);
        g.d[0] = {INh, INl, Wkh, Wkl, b_k, nullptr, Kph, Kpl, 1.0f, 1};
        gemm_mfma_batch<<<ggrid1, 256, 0, stream>>>(g, MROWS, D_MODEL, D_MODEL);

        s1.src[0] = value;
        split_multi<<<dim3((unsigned)(AE / 8 / 256), 1), 256, 0, stream>>>(s1, an8);
        g.d[0] = {INh, INl, Wvh, Wvl, b_v, nullptr, VT, nullptr, 1.0f, 2};
        gemm_mfma_batch<<<ggrid1, 256, 0, stream>>>(g, MROWS, D_MODEL, D_MODEL);

        flash_attn<<<fgrid, 512, 0, stream>>>(Qph, Qpl, Kph, Kpl, VT, Ch, Cl);

        g.d[0] = {Ch, Cl, Woh, Wol, b_o, out, nullptr, nullptr, 1.0f, 0};
        gemm_mfma_batch<<<ggrid1, 256, 0, stream>>>(g, MROWS, D_MODEL, D_MODEL);
    }
}

// Round 17
// 306.236 us; speedup vs baseline: 1.0623x; 1.0623x over previous
//
#include <hip/hip_runtime.h>
#include <math.h>

#define D_MODEL 1024
#define NUM_HEADS 16
#define DK 64
#define BATCH 2
#define NSEQ 2048
#define MROWS (BATCH * NSEQ)   // 4096

typedef __attribute__((ext_vector_type(8))) short bf16x8;
typedef __attribute__((ext_vector_type(4))) short s16x4;
typedef __attribute__((ext_vector_type(4))) float f32x4;
typedef unsigned short u16;

static __device__ __forceinline__ u16 f2bf_rne(float x) {
    union { float f; unsigned u; } v; v.f = x;
    unsigned r = v.u + 0x7fffu + ((v.u >> 16) & 1u);
    return (u16)(r >> 16);
}
static __device__ __forceinline__ void split_bf16(float x, u16& hi, u16& lo) {
    union { float f; unsigned u; } v; v.f = x;
    unsigned hb = v.u & 0xffff0000u;
    hi = (u16)(hb >> 16);
    union { unsigned u; float f; } hv; hv.u = hb;
    lo = f2bf_rne(x - hv.f);
}
// HW packed f32->bf16 RNE: dst.lo = bf16(a), dst.hi = bf16(b). Bit-identical
// to f2bf_rne for finite values (both round-to-nearest-even).
static __device__ __forceinline__ unsigned cvt_pk_bf16(float a, float b) {
    unsigned w;
    asm("v_cvt_pk_bf16_f32 %0, %1, %2" : "=v"(w) : "v"(a), "v"(b));
    return w;
}
static __device__ __forceinline__ float max3f(float a, float b, float c) {
    return fmaxf(fmaxf(a, b), c);   // clang fuses to v_max3_f32
}

#define AS1 __attribute__((address_space(1)))
#define AS3 __attribute__((address_space(3)))
static __device__ __forceinline__ void gl_lds16(const void* g, void* l) {
    __builtin_amdgcn_global_load_lds((AS1 void*)(uintptr_t)g, (AS3 void*)l, 16, 0, 0);
}

// ---------------------------------------------------------------------------
// fp32 -> split bf16 planes, up to 4 tensors per launch (blockIdx.y).
// ---------------------------------------------------------------------------
struct SplitN { const float* src[4]; u16* h[4]; u16* l[4]; };
__global__ __launch_bounds__(256)
void split_multi(SplitN args, int n8)
{
    const int w = blockIdx.y;
    const int i = blockIdx.x * 256 + threadIdx.x;
    if (i >= n8) return;
    const float* src = args.src[w];
    float4 a = ((const float4*)src)[2 * i];
    float4 b = ((const float4*)src)[2 * i + 1];
    float x[8] = {a.x, a.y, a.z, a.w, b.x, b.y, b.z, b.w};
    u16 hh[8], ll[8];
#pragma unroll
    for (int j = 0; j < 8; ++j) split_bf16(x[j], hh[j], ll[j]);
    *(uint4*)(args.h[w] + 8 * (size_t)i) = *(uint4*)hh;
    *(uint4*)(args.l[w] + 8 * (size_t)i) = *(uint4*)ll;
}

// ---------------------------------------------------------------------------
// Batched MFMA GEMM (R5-proven structure, R7 grids): BM=128 BN=64 BK=64.
// mode 0: fp32 out. mode 1: split planes. mode 2: V -> per-head transposed
// RNE plane, R16: KEY-INTERLEAVED within each 32-key group so flash's PV
// A-frag is ONE aligned b128 (pos 8u+j <- key (j<4)? 4u+j : 16+4u+j-4).
// GEMM tile-shape experiments (R14/R15 wide BN=128) measured NEUTRAL ->
// reverted to this measured-best config; 2-barrier structure is the ceiling
// (8-phase escape blocked: split-bf16 doubles its LDS footprint past 160KB).
// ---------------------------------------------------------------------------
#define GBM 128
#define GBN 64
#define GBK 64

struct GemmDesc {
    const u16 *Ah, *Al, *Wh, *Wl;
    const float* bias;
    float* outF;
    u16 *outH, *outL;
    float scale;
    int mode;
};
struct GemmBatch { GemmDesc d[3]; };

__global__ __launch_bounds__(256)
void gemm_mfma_batch(GemmBatch batch, int M, int N, int K)
{
    __shared__ u16 SM[2 * GBM * GBK + 2 * GBN * GBK];   // 48 KB pool
    u16* As_h = SM;                       // [128][64]
    u16* As_l = SM + GBM * GBK;
    u16* Ws_h = SM + 2 * GBM * GBK;       // [64][64]
    u16* Ws_l = SM + 2 * GBM * GBK + GBN * GBK;

    const GemmDesc d = batch.d[blockIdx.z];
    const int tid  = threadIdx.x;
    const int wv   = tid >> 6, lane = tid & 63;
    const int quad = lane >> 4, lcol = lane & 15;
    const int bm = blockIdx.x * GBM, bn = blockIdx.y * GBN;   // x = M (XCD fix)
    const int wm = (wv >> 1) * 64, wn = (wv & 1) * 32;
    const int sj = lane >> 3, sg = lane & 7;
    const int sgx8 = ((sg ^ sj) << 3);

    f32x4 acc[4][2];
#pragma unroll
    for (int i = 0; i < 4; ++i)
#pragma unroll
        for (int j = 0; j < 2; ++j) acc[i][j] = (f32x4){0.f, 0.f, 0.f, 0.f};

    for (int k0 = 0; k0 < K; k0 += GBK) {
        __syncthreads();
#pragma unroll
        for (int c = 0; c < 4; ++c) {
            const int r0 = wv * 32 + c * 8;
            gl_lds16(d.Ah + (size_t)(bm + r0 + sj) * K + k0 + sgx8, As_h + r0 * GBK);
            gl_lds16(d.Al + (size_t)(bm + r0 + sj) * K + k0 + sgx8, As_l + r0 * GBK);
        }
#pragma unroll
        for (int c = 0; c < 2; ++c) {
            const int r0 = wv * 16 + c * 8;
            gl_lds16(d.Wh + (size_t)(bn + r0 + sj) * K + k0 + sgx8, Ws_h + r0 * GBK);
            gl_lds16(d.Wl + (size_t)(bn + r0 + sj) * K + k0 + sgx8, Ws_l + r0 * GBK);
        }
        __syncthreads();

#pragma unroll
        for (int hf = 0; hf < 2; ++hf) {
            const int sl = ((((hf << 2) + quad) ^ (lcol & 7)) << 3);
            bf16x8 bh[2], bl[2];
#pragma unroll
            for (int j = 0; j < 2; ++j) {
                const int rn = wn + (j << 4) + lcol;
                bh[j] = *(const bf16x8*)(Ws_h + rn * GBK + sl);
                bl[j] = *(const bf16x8*)(Ws_l + rn * GBK + sl);
            }
#pragma unroll
            for (int i = 0; i < 4; ++i) {
                const int rm = wm + (i << 4) + lcol;
                bf16x8 ah = *(const bf16x8*)(As_h + rm * GBK + sl);
                bf16x8 al = *(const bf16x8*)(As_l + rm * GBK + sl);
#pragma unroll
                for (int j = 0; j < 2; ++j) {
                    acc[i][j] = __builtin_amdgcn_mfma_f32_16x16x32_bf16(ah, bh[j], acc[i][j], 0, 0, 0);
                    acc[i][j] = __builtin_amdgcn_mfma_f32_16x16x32_bf16(al, bh[j], acc[i][j], 0, 0, 0);
                    acc[i][j] = __builtin_amdgcn_mfma_f32_16x16x32_bf16(ah, bl[j], acc[i][j], 0, 0, 0);
                }
            }
        }
    }

    if (d.mode == 2) {
        // V path: re-transpose via LDS, write Vt[b][h][d][n] single RNE plane,
        // KEY-INTERLEAVED per 32-group (R16): output uint4 u holds keys
        // {4u..4u+3, 16+4u..16+4u+3} so flash PV reads one b128 per frag.
        const int TS = 136;
        u16* T = SM;
        __syncthreads();
#pragma unroll
        for (int j = 0; j < 2; ++j) {
            const int cl = wn + (j << 4) + lcol;       // d-local 0..63
            const float bj = d.bias[bn + cl];
#pragma unroll
            for (int i = 0; i < 4; ++i) {
                const int r0 = wm + (i << 4) + quad * 4;
                u16 pk[4];
#pragma unroll
                for (int r = 0; r < 4; ++r) pk[r] = f2bf_rne(acc[i][j][r] + bj);
                *(ushort4*)(T + cl * TS + r0) = *(ushort4*)pk;
            }
        }
        __syncthreads();
        const int dd = tid >> 2, pt = tid & 3;
        const int bidx = bm >> 11, hh = bn >> 6;
        u16* dst = d.outH + ((size_t)(bidx * NUM_HEADS + hh) * DK + dd) * NSEQ
                 + (bm & (NSEQ - 1)) + pt * 32;
        const u16* src = T + dd * TS + pt * 32;
#pragma unroll
        for (int u = 0; u < 4; ++u) {
            ushort4 lo = *(const ushort4*)(src + 4 * u);        // keys 4u..4u+3
            ushort4 hi = *(const ushort4*)(src + 16 + 4 * u);   // keys 16+4u..
            u16 w[8] = {lo.x, lo.y, lo.z, lo.w, hi.x, hi.y, hi.z, hi.w};
            ((uint4*)dst)[u] = *(uint4*)w;
        }
        return;
    }

#pragma unroll
    for (int j = 0; j < 2; ++j) {
        const int col = bn + wn + (j << 4) + lcol;
        const float bj = d.bias[col];
#pragma unroll
        for (int i = 0; i < 4; ++i) {
#pragma unroll
            for (int r = 0; r < 4; ++r) {
                const int row = bm + wm + (i << 4) + quad * 4 + r;
                const float v = (acc[i][j][r] + bj) * d.scale;
                const size_t o = (size_t)row * N + col;
                if (d.mode == 0) {
                    d.outF[o] = v;
                } else {
                    u16 hi, lo;
                    split_bf16(v, hi, lo);
                    d.outH[o] = hi;
                    d.outL[o] = lo;
                }
            }
        }
    }
}

// ---------------------------------------------------------------------------
// Flash attention: R12 structure (measured 98.6-101.3 us) + R16 PV change:
// Vt plane arrives key-interleaved, so each PV A-frag is ONE ds_read_b128
// (was 2x ds_read_b64 + 8-elem VALU repack). Element j of the b128 equals
// old aV[j] exactly -> bit-identical PV. Targets the measured-saturated LDS
// pipe (R12 arithmetic: ~240K LDS cyc vs 237K kernel cyc) + VALUBusy 40.
// ---------------------------------------------------------------------------
__global__ __launch_bounds__(512)
void flash_attn(const u16* __restrict__ Qh_g, const u16* __restrict__ Ql_g,
                const u16* __restrict__ Kh_g, const u16* __restrict__ Kl_g,
                const u16* __restrict__ Vt_g,
                u16* __restrict__ Ch_g, u16* __restrict__ Cl_g)
{
    __shared__ __align__(16) u16 Ks_h[2][64][72], Ks_l[2][64][72];
    __shared__ __align__(16) u16 Vs[2][64][72];    // [buf][d][key-interleaved]

    const int tid  = threadIdx.x;
    const int wv   = tid >> 6;          // 0..7
    const int lane = tid & 63;
    const int quad = lane >> 4;
    const int lcol = lane & 15;
    const int h    = blockIdx.x;        // XCD: head fast index (h%8 -> XCD)
    const int q0   = blockIdx.y << 7;   // 128 q per block
    const int b    = blockIdx.z;
    const size_t hbase  = (size_t)b * NSEQ * D_MODEL + (size_t)h * DK;
    const size_t vtbase = (size_t)(b * NUM_HEADS + h) * DK * NSEQ;

    // wave wv owns q rows q0 + wv*16 + lcol
    bf16x8 bQh[2], bQl[2];
    {
        const u16* qh = Qh_g + hbase + (size_t)(q0 + wv * 16 + lcol) * D_MODEL;
        const u16* ql = Ql_g + hbase + (size_t)(q0 + wv * 16 + lcol) * D_MODEL;
#pragma unroll
        for (int c = 0; c < 2; ++c) {
            bQh[c] = *(const bf16x8*)(qh + c * 32 + quad * 8);
            bQl[c] = *(const bf16x8*)(ql + c * 32 + quad * 8);
        }
    }

    f32x4 Oacc[4];
#pragma unroll
    for (int t = 0; t < 4; ++t) Oacc[t] = (f32x4){0.f, 0.f, 0.f, 0.f};
    float mrow = -INFINITY;
    float lrow = 0.f;

    // staging: 512 threads cover one 64x64 u16 plane with one uint4 each
    const int lr  = tid >> 3;           // 0..63
    const int lc8 = (tid & 7) << 3;     // u16 col 0,8,..,56

    const int NT = NSEQ / 64;           // 32 (>= 2)
    const u16* gKh = Kh_g + hbase + (size_t)lr * D_MODEL + lc8;   // row=key
    const u16* gKl = Kl_g + hbase + (size_t)lr * D_MODEL + lc8;
    const u16* gV  = Vt_g + vtbase + (size_t)lr * NSEQ + lc8;     // row=d

    // prologue: tile 0 -> buf0 (one exposed vmcnt drain, once); issue tile 1
    uint4 s0 = *(const uint4*)(gKh);
    uint4 s1 = *(const uint4*)(gKl);
    uint4 s2 = *(const uint4*)(gV);
    *(uint4*)&Ks_h[0][lr][lc8] = s0;
    *(uint4*)&Ks_l[0][lr][lc8] = s1;
    *(uint4*)&Vs[0][lr][lc8]   = s2;
    s0 = *(const uint4*)(gKh + (size_t)64 * D_MODEL);
    s1 = *(const uint4*)(gKl + (size_t)64 * D_MODEL);
    s2 = *(const uint4*)(gV + 64);
    __syncthreads();

    for (int kt = 0; kt < NT; ++kt) {
        const int cur = kt & 1;
        const u16 (*Kh)[72] = Ks_h[cur];
        const u16 (*Kl)[72] = Ks_l[cur];
        const u16 (*Vv)[72] = Vs[cur];

        f32x4 S[4];
        __builtin_amdgcn_s_setprio(1);
#pragma unroll
        for (int t = 0; t < 4; ++t) {
            bf16x8 aKh0 = *(const bf16x8*)&Kh[(t << 4) + lcol][quad * 8];
            bf16x8 aKh1 = *(const bf16x8*)&Kh[(t << 4) + lcol][32 + quad * 8];
            bf16x8 aKl0 = *(const bf16x8*)&Kl[(t << 4) + lcol][quad * 8];
            bf16x8 aKl1 = *(const bf16x8*)&Kl[(t << 4) + lcol][32 + quad * 8];
            f32x4 a = (f32x4){0.f, 0.f, 0.f, 0.f};
            a = __builtin_amdgcn_mfma_f32_16x16x32_bf16(aKh0, bQh[0], a, 0, 0, 0);
            a = __builtin_amdgcn_mfma_f32_16x16x32_bf16(aKh1, bQh[1], a, 0, 0, 0);
            a = __builtin_amdgcn_mfma_f32_16x16x32_bf16(aKl0, bQh[0], a, 0, 0, 0);
            a = __builtin_amdgcn_mfma_f32_16x16x32_bf16(aKl1, bQh[1], a, 0, 0, 0);
            a = __builtin_amdgcn_mfma_f32_16x16x32_bf16(aKh0, bQl[0], a, 0, 0, 0);
            a = __builtin_amdgcn_mfma_f32_16x16x32_bf16(aKh1, bQl[1], a, 0, 0, 0);
            S[t] = a;
        }
        __builtin_amdgcn_s_setprio(0);

        bf16x8 pb[2];
        {
            // ---- max over 16 per-lane scores, v_max3 tree ----
            float m0 = max3f(S[0][0], S[0][1], S[0][2]);
            float m1 = max3f(S[0][3], S[1][0], S[1][1]);
            float m2 = max3f(S[1][2], S[1][3], S[2][0]);
            float m3 = max3f(S[2][1], S[2][2], S[2][3]);
            float m4 = max3f(S[3][0], S[3][1], S[3][2]);
            float m16 = fmaxf(max3f(m0, m1, S[3][3]), fmaxf(m2, fmaxf(m3, m4)));
            m16 = fmaxf(m16, __shfl_xor(m16, 16, 64));
            m16 = fmaxf(m16, __shfl_xor(m16, 32, 64));
            const float mn = fmaxf(mrow, m16);
            const float alpha = __expf(mrow - mn);
            mrow = mn;

            float p[4][4];
            float psum = 0.f;
#pragma unroll
            for (int t = 0; t < 4; ++t)
#pragma unroll
                for (int r = 0; r < 4; ++r) {
                    const float pv = __expf(S[t][r] - mn);
                    p[t][r] = pv;
                    psum += pv;
                }
            psum += __shfl_xor(psum, 16, 64);
            psum += __shfl_xor(psum, 32, 64);
            lrow = alpha * lrow + psum;

            // ---- pack P^T: pb[c] = {p[2c][0..3], p[2c+1][0..3]} ----
            union { unsigned w[4]; bf16x8 v; } P0, P1;
            P0.w[0] = cvt_pk_bf16(p[0][0], p[0][1]);
            P0.w[1] = cvt_pk_bf16(p[0][2], p[0][3]);
            P0.w[2] = cvt_pk_bf16(p[1][0], p[1][1]);
            P0.w[3] = cvt_pk_bf16(p[1][2], p[1][3]);
            P1.w[0] = cvt_pk_bf16(p[2][0], p[2][1]);
            P1.w[1] = cvt_pk_bf16(p[2][2], p[2][3]);
            P1.w[2] = cvt_pk_bf16(p[3][0], p[3][1]);
            P1.w[3] = cvt_pk_bf16(p[3][2], p[3][3]);
            pb[0] = P0.v;
            pb[1] = P1.v;

#pragma unroll
            for (int t = 0; t < 4; ++t)
#pragma unroll
                for (int r = 0; r < 4; ++r) Oacc[t][r] *= alpha;
        }

        __builtin_amdgcn_s_setprio(1);
#pragma unroll
        for (int dt = 0; dt < 4; ++dt) {
            const u16* vr = &Vv[(dt << 4) + lcol][0];
#pragma unroll
            for (int c = 0; c < 2; ++c) {
                // key-interleaved layout: one b128 = old {alo[0..3],ahi[0..3]}
                bf16x8 aV = *(const bf16x8*)(vr + c * 32 + quad * 8);
                Oacc[dt] = __builtin_amdgcn_mfma_f32_16x16x32_bf16(aV, pb[c], Oacc[dt], 0, 0, 0);
            }
        }
        __builtin_amdgcn_s_setprio(0);

        // write NEXT tile (staged in regs last iteration) into the other
        // buffer; its readers (iter kt+1) are behind the barrier below, its
        // previous readers (iter kt-1) finished before the last barrier.
        if (kt + 1 < NT) {
            *(uint4*)&Ks_h[cur ^ 1][lr][lc8] = s0;
            *(uint4*)&Ks_l[cur ^ 1][lr][lc8] = s1;
            *(uint4*)&Vs[cur ^ 1][lr][lc8]   = s2;
            if (kt + 2 < NT) {
                const size_t ko = (size_t)(kt + 2) << 6;
                s0 = *(const uint4*)(gKh + ko * D_MODEL);
                s1 = *(const uint4*)(gKl + ko * D_MODEL);
                s2 = *(const uint4*)(gV + ko);
            }
        }
        __syncthreads();
    }

    {
        const float inv = 1.f / lrow;
        const size_t base = hbase + (size_t)(q0 + wv * 16 + lcol) * D_MODEL;
#pragma unroll
        for (int dt = 0; dt < 4; ++dt) {
            u16 hv[4], lv[4];
#pragma unroll
            for (int r = 0; r < 4; ++r)
                split_bf16(Oacc[dt][r] * inv, hv[r], lv[r]);
            const size_t o = base + (dt << 4) + quad * 4;
            *(ushort4*)(Ch_g + o) = *(ushort4*)hv;
            *(ushort4*)(Cl_g + o) = *(ushort4*)lv;
        }
    }
}

// ---------------------------------------------------------------------------
extern "C" void kernel_launch(void* const* d_in, const int* in_sizes, int n_in,
                              void* d_out, int out_size, void* d_ws, size_t ws_size,
                              hipStream_t stream)
{
    const float* query = (const float*)d_in[0];
    const float* key_i = (const float*)d_in[1];
    const float* value = (const float*)d_in[2];
    const float* w_q   = (const float*)d_in[3];
    const float* b_q   = (const float*)d_in[4];
    const float* w_k   = (const float*)d_in[5];
    const float* b_k   = (const float*)d_in[6];
    const float* w_v   = (const float*)d_in[7];
    const float* b_v   = (const float*)d_in[8];
    const float* w_o   = (const float*)d_in[9];
    const float* b_o   = (const float*)d_in[10];
    float* out = (float*)d_out;

    const size_t WE = (size_t)D_MODEL * D_MODEL;   // 1M
    const size_t AE = (size_t)MROWS * D_MODEL;     // 4M

    u16* p = (u16*)d_ws;
    u16* Wqh = p;            u16* Wql = Wqh + WE;
    u16* Wkh = Wql + WE;     u16* Wkl = Wkh + WE;
    u16* Wvh = Wkl + WE;     u16* Wvl = Wvh + WE;
    u16* Woh = Wvl + WE;     u16* Wol = Woh + WE;
    u16* base = Wol + WE;

    SplitN ws4;
    ws4.src[0] = w_q; ws4.h[0] = Wqh; ws4.l[0] = Wql;
    ws4.src[1] = w_k; ws4.h[1] = Wkh; ws4.l[1] = Wkl;
    ws4.src[2] = w_v; ws4.h[2] = Wvh; ws4.l[2] = Wvl;
    ws4.src[3] = w_o; ws4.h[3] = Woh; ws4.l[3] = Wol;
    split_multi<<<dim3((unsigned)(WE / 8 / 256), 4), 256, 0, stream>>>(ws4, (int)(WE / 8));

    const float qscale = 0.125f;
    // XCD-aware grids: x = dimension whose blocks SHARE data.
    dim3 fgrid(NUM_HEADS, NSEQ / 128, BATCH);        // (16,16,2), x = head
    dim3 ggrid3(MROWS / GBM, D_MODEL / GBN, 3);      // (32,16,3), x = M
    dim3 ggrid1(MROWS / GBM, D_MODEL / GBN, 1);      // (32,16,1), x = M
    const int an8 = (int)(AE / 8);

    const size_t fused_bytes = 2 * (8 * WE + 11 * AE);   // 104 MB
    if (ws_size >= fused_bytes) {
        u16* INqh = base;          u16* INql = INqh + AE;
        u16* INkh = INql + AE;     u16* INkl = INkh + AE;
        u16* INvh = INkl + AE;     u16* INvl = INvh + AE;
        u16* Qph  = INvl + AE;     u16* Qpl  = Qph + AE;
        u16* Kph  = Qpl + AE;      u16* Kpl  = Kph + AE;
        u16* VT   = Kpl + AE;
        u16* Ch   = INqh;          u16* Cl   = INql;    // alias, dead after QKV

        SplitN as3;
        as3.src[0] = query; as3.h[0] = INqh; as3.l[0] = INql;
        as3.src[1] = key_i; as3.h[1] = INkh; as3.l[1] = INkl;
        as3.src[2] = value; as3.h[2] = INvh; as3.l[2] = INvl;
        as3.src[3] = query; as3.h[3] = INqh; as3.l[3] = INql;  // unused
        split_multi<<<dim3((unsigned)(AE / 8 / 256), 3), 256, 0, stream>>>(as3, an8);

        GemmBatch gb;
        gb.d[0] = {INqh, INql, Wqh, Wql, b_q, nullptr, Qph, Qpl, qscale, 1};
        gb.d[1] = {INkh, INkl, Wkh, Wkl, b_k, nullptr, Kph, Kpl, 1.0f,   1};
        gb.d[2] = {INvh, INvl, Wvh, Wvl, b_v, nullptr, VT,  nullptr, 1.0f, 2};
        gemm_mfma_batch<<<ggrid3, 256, 0, stream>>>(gb, MROWS, D_MODEL, D_MODEL);

        flash_attn<<<fgrid, 512, 0, stream>>>(Qph, Qpl, Kph, Kpl, VT, Ch, Cl);

        GemmBatch go;
        go.d[0] = {Ch, Cl, Woh, Wol, b_o, out, nullptr, nullptr, 1.0f, 0};
        gemm_mfma_batch<<<ggrid1, 256, 0, stream>>>(go, MROWS, D_MODEL, D_MODEL);
    } else {
        u16* INh = base;           u16* INl = INh + AE;
        u16* Qph = INl + AE;       u16* Qpl = Qph + AE;
        u16* Kph = Qpl + AE;       u16* Kpl = Kph + AE;
        u16* VT  = Kpl + AE;
        u16* Ch  = INh;            u16* Cl  = INl;

        SplitN s1;
        s1.src[0] = query; s1.h[0] = INh; s1.l[0] = INl;
        s1.src[1] = s1.src[2] = s1.src[3] = query;
        s1.h[1] = s1.h[2] = s1.h[3] = INh; s1.l[1] = s1.l[2] = s1.l[3] = INl;

        GemmBatch g;
        s1.src[0] = query;
        split_multi<<<dim3((unsigned)(AE / 8 / 256), 1), 256, 0, stream>>>(s1, an8);
        g.d[0] = {INh, INl, Wqh, Wql, b_q, nullptr, Qph, Qpl, qscale, 1};
        gemm_mfma_batch<<<ggrid1, 256, 0, stream>>>(g, MROWS, D_MODEL, D_MODEL);

        s1.src[0] = key_i;
        split_multi<<<dim3((unsigned)(AE / 8 / 256), 1), 256, 0, stream>>>(s1, an8);
        g.d[0] = {INh, INl, Wkh, Wkl, b_k, nullptr, Kph, Kpl, 1.0f, 1};
        gemm_mfma_batch<<<ggrid1, 256, 0, stream>>>(g, MROWS, D_MODEL, D_MODEL);

        s1.src[0] = value;
        split_multi<<<dim3((unsigned)(AE / 8 / 256), 1), 256, 0, stream>>>(s1, an8);
        g.d[0] = {INh, INl, Wvh, Wvl, b_v, nullptr, VT, nullptr, 1.0f, 2};
        gemm_mfma_batch<<<ggrid1, 256, 0, stream>>>(g, MROWS, D_MODEL, D_MODEL);

        flash_attn<<<fgrid, 512, 0, stream>>>(Qph, Qpl, Kph, Kpl, VT, Ch, Cl);

        g.d[0] = {Ch, Cl, Woh, Wol, b_o, out, nullptr, nullptr, 1.0f, 0};
        gemm_mfma_batch<<<ggrid1, 256, 0, stream>>>(g, MROWS, D_MODEL, D_MODEL);
    }
}